// Round 1
// baseline (236.410 us; speedup 1.0000x reference)
//
#include <hip/hip_runtime.h>
#include <hip/hip_bf16.h>

// TDNN as GEMM: out[m,o] = relu(bias[o] + sum_kk A[m,kk] * W[kk,o])
//   A[m,kk] = x[b, t+kw, c]  (m=b*996+t, kk=kw*512+c) -> contiguous slice of x
//   W[kk,o] = kernel[o, c, kw]; stored transposed (Wt[o][kk]) for K-contiguous reads.

#define BATCH 64
#define SEQ   1000
#define CIN   512
#define COUT  512
#define KW    5
#define TOUT  996            // SEQ - KW + 1
#define KTOT  2560           // CIN*KW
#define MTOT  63744          // BATCH*TOUT
#define MT    498            // MTOT/128 (exact)
#define NT    4              // COUT/128

typedef __bf16 bf16x8 __attribute__((ext_vector_type(8)));
typedef float  f32x4  __attribute__((ext_vector_type(4)));

__device__ __forceinline__ void gload_lds16(const void* g, void* l) {
  __builtin_amdgcn_global_load_lds(
      (const __attribute__((address_space(1))) void*)g,
      (__attribute__((address_space(3))) void*)l,
      16, 0, 0);
}

// ---- x fp32 -> bf16 (vectorized, 8 elems/thread) ----
__global__ void cvt_x_kernel(const float* __restrict__ x, __bf16* __restrict__ xb, int n) {
  int i = (blockIdx.x * blockDim.x + threadIdx.x) * 8;
  if (i >= n) return;
  float4 f0 = *(const float4*)(x + i);
  float4 f1 = *(const float4*)(x + i + 4);
  bf16x8 v;
  v[0] = (__bf16)f0.x; v[1] = (__bf16)f0.y; v[2] = (__bf16)f0.z; v[3] = (__bf16)f0.w;
  v[4] = (__bf16)f1.x; v[5] = (__bf16)f1.y; v[6] = (__bf16)f1.z; v[7] = (__bf16)f1.w;
  *(bf16x8*)(xb + i) = v;
}

// ---- kernel [O][C][KW] fp32 -> Wt [O][KTOT] bf16, Wt[o][kw*512+c] = kernel[o][c][kw] ----
__global__ void cvt_w_kernel(const float* __restrict__ k, __bf16* __restrict__ wt) {
  int idx = blockIdx.x * blockDim.x + threadIdx.x;   // over 512*2560
  if (idx >= COUT * KTOT) return;
  int o  = idx / KTOT;
  int r  = idx - o * KTOT;
  int kw = r >> 9;           // r / 512
  int c  = r & 511;
  wt[idx] = (__bf16)k[(o * CIN + c) * KW + kw];
}

// ---- main GEMM: 128x128 tile, BK=32, 4 waves (2x2), mfma 16x16x32 bf16 ----
__global__ __launch_bounds__(256)
void tdnn_gemm_kernel(const __bf16* __restrict__ Xb, const __bf16* __restrict__ Wt,
                      const float* __restrict__ bias, float* __restrict__ out) {
  __shared__ __align__(16) __bf16 Alds[128 * 32];
  __shared__ __align__(16) __bf16 Blds[128 * 32];

  const int tid  = threadIdx.x;
  const int wave = tid >> 6;
  const int lane = tid & 63;

  // bijective XCD swizzle: 1992 blocks = 8 * 249; co-locate the 4 N-tiles of
  // each A-panel (consecutive swz) on one XCD's L2.
  int bid = blockIdx.x;
  int swz = (bid & 7) * (MT * NT / 8) + (bid >> 3);
  const int bm = swz >> 2;        // 0..497
  const int bn = swz & 3;         // 0..3
  const int m0 = bm * 128;
  const int n0 = bn * 128;

  // ---- staging geometry: tile = 128 rows x 32 k-elems bf16 = 8192 B = 8 chunks
  // of 1024 B; wave w stages chunks 2w, 2w+1. Lane dest byte = chunk*1024 +
  // lane*16 -> row = chunk*16 + lane/4, k-off = (lane&3)*8 elems.
  const int rA0 = (wave * 2 + 0) * 16 + (lane >> 2);
  const int rA1 = (wave * 2 + 1) * 16 + (lane >> 2);
  const int kof = (lane & 3) * 8;

  // A rows: m = m0 + r ; b = m/996, t = m%996 ; row base = (b*1000+t)*512
  int mA0 = m0 + rA0, mA1 = m0 + rA1;
  int b0 = mA0 / TOUT, t0 = mA0 - b0 * TOUT;
  int b1 = mA1 / TOUT, t1 = mA1 - b1 * TOUT;
  const __bf16* gA0 = Xb + ((size_t)(b0 * SEQ + t0) * CIN) + kof;
  const __bf16* gA1 = Xb + ((size_t)(b1 * SEQ + t1) * CIN) + kof;
  const __bf16* gB0 = Wt + (size_t)(n0 + rA0) * KTOT + kof;
  const __bf16* gB1 = Wt + (size_t)(n0 + rA1) * KTOT + kof;

  char* ldsA0 = (char*)Alds + (wave * 2 + 0) * 1024;
  char* ldsA1 = (char*)Alds + (wave * 2 + 1) * 1024;
  char* ldsB0 = (char*)Blds + (wave * 2 + 0) * 1024;
  char* ldsB1 = (char*)Blds + (wave * 2 + 1) * 1024;

  // wave -> 64x64 output quadrant
  const int wr = wave >> 1;
  const int wc = wave & 1;

  f32x4 acc[4][4];
  const f32x4 z = {0.f, 0.f, 0.f, 0.f};
#pragma unroll
  for (int i = 0; i < 4; i++)
#pragma unroll
    for (int j = 0; j < 4; j++) acc[i][j] = z;

  const int frow = lane & 15;          // fragment row (A) / col (B)
  const int fk   = (lane >> 4) * 8;    // k offset within BK=32

  for (int kk = 0; kk < KTOT; kk += 32) {
    gload_lds16(gA0 + kk, ldsA0);
    gload_lds16(gA1 + kk, ldsA1);
    gload_lds16(gB0 + kk, ldsB0);
    gload_lds16(gB1 + kk, ldsB1);
    __syncthreads();   // compiler emits s_waitcnt vmcnt(0) before s_barrier

    bf16x8 a[4], b[4];
#pragma unroll
    for (int i = 0; i < 4; i++)
      a[i] = *(const bf16x8*)&Alds[(wr * 64 + i * 16 + frow) * 32 + fk];
#pragma unroll
    for (int i = 0; i < 4; i++)
      b[i] = *(const bf16x8*)&Blds[(wc * 64 + i * 16 + frow) * 32 + fk];

#pragma unroll
    for (int i = 0; i < 4; i++)
#pragma unroll
      for (int j = 0; j < 4; j++)
        acc[i][j] = __builtin_amdgcn_mfma_f32_16x16x32_bf16(a[i], b[j], acc[i][j], 0, 0, 0);

    __syncthreads();
  }

  // ---- epilogue: bias + relu + store. C/D map: col=lane&15, row=(lane>>4)*4+reg
  const int ccol = lane & 15;
  const int crow = (lane >> 4) * 4;
  float bv[4];
#pragma unroll
  for (int nj = 0; nj < 4; nj++)
    bv[nj] = bias[n0 + wc * 64 + nj * 16 + ccol];

#pragma unroll
  for (int mi = 0; mi < 4; mi++) {
    const int mrow = m0 + wr * 64 + mi * 16 + crow;
#pragma unroll
    for (int nj = 0; nj < 4; nj++) {
      const int ocol = n0 + wc * 64 + nj * 16 + ccol;
#pragma unroll
      for (int j = 0; j < 4; j++) {
        float v = acc[mi][nj][j] + bv[nj];
        v = v > 0.f ? v : 0.f;
        out[(size_t)(mrow + j) * COUT + ocol] = v;
      }
    }
  }
}

extern "C" void kernel_launch(void* const* d_in, const int* in_sizes, int n_in,
                              void* d_out, int out_size, void* d_ws, size_t ws_size,
                              hipStream_t stream) {
  const float* x      = (const float*)d_in[0];   // [64,1000,512] fp32
  const float* kernel = (const float*)d_in[1];   // [512,512,5]   fp32
  const float* bias   = (const float*)d_in[2];   // [512]         fp32
  float* out          = (float*)d_out;           // [64,996,512]  fp32

  // workspace: xb (65,536,000 B) | wt (2,621,440 B) -> ~68.2 MB total
  __bf16* xb = (__bf16*)d_ws;
  __bf16* wt = (__bf16*)((char*)d_ws + (size_t)BATCH * SEQ * CIN * 2);

  const int nx = BATCH * SEQ * CIN;              // 32,768,000
  cvt_x_kernel<<<nx / 8 / 256, 256, 0, stream>>>(x, xb, nx);
  cvt_w_kernel<<<(COUT * KTOT + 255) / 256, 256, 0, stream>>>(kernel, wt);
  tdnn_gemm_kernel<<<MT * NT, 256, 0, stream>>>(xb, wt, bias, out);
}

// Round 2
// 193.693 us; speedup vs baseline: 1.2205x; 1.2205x over previous
//
#include <hip/hip_runtime.h>
#include <hip/hip_bf16.h>

// TDNN as GEMM, 256x256-tile 4-phase pipelined schedule (T2+T3+T4+T5).
//   out[m,o] = relu(bias[o] + sum_kk A[m,kk]*W[kk,o])
//   A[m,kk] = x[b, t+kw, c] (contiguous 2560-elem slice), W[kk,o] = kernel[o,c,kw]

#define BATCH 64
#define SEQ   1000
#define CIN   512
#define COUT  512
#define TOUT  996
#define KTOT  2560
#define MTOT  63744
#define NKT   40            // K-tiles of 64
#define MT    249           // MTOT/256
#define NT    2             // COUT/256
#define NWG   (MT*NT)       // 498

typedef __bf16 bf16x8 __attribute__((ext_vector_type(8)));
typedef float  f32x4  __attribute__((ext_vector_type(4)));

__device__ __forceinline__ void gload_lds16(const void* g, void* l) {
  __builtin_amdgcn_global_load_lds(
      (const __attribute__((address_space(1))) void*)g,
      (__attribute__((address_space(3))) void*)l, 16, 0, 0);
}

#define BAR()   __builtin_amdgcn_s_barrier()
#define LGKM0() asm volatile("s_waitcnt lgkmcnt(0)" ::: "memory")
#define VM4()   asm volatile("s_waitcnt vmcnt(4)" ::: "memory")
#define VM0()   asm volatile("s_waitcnt vmcnt(0)" ::: "memory")
#define PRIO(x) __builtin_amdgcn_s_setprio(x)

// ---- x fp32 -> bf16 ----
__global__ void cvt_x_kernel(const float* __restrict__ x, __bf16* __restrict__ xb, int n) {
  int i = (blockIdx.x * blockDim.x + threadIdx.x) * 8;
  if (i >= n) return;
  float4 f0 = *(const float4*)(x + i);
  float4 f1 = *(const float4*)(x + i + 4);
  bf16x8 v;
  v[0] = (__bf16)f0.x; v[1] = (__bf16)f0.y; v[2] = (__bf16)f0.z; v[3] = (__bf16)f0.w;
  v[4] = (__bf16)f1.x; v[5] = (__bf16)f1.y; v[6] = (__bf16)f1.z; v[7] = (__bf16)f1.w;
  *(bf16x8*)(xb + i) = v;
}

// ---- kernel [O][C][KW] fp32 -> Wt [O][KTOT] bf16, Wt[o][kw*512+c] ----
__global__ void cvt_w_kernel(const float* __restrict__ k, __bf16* __restrict__ wt) {
  int idx = blockIdx.x * blockDim.x + threadIdx.x;
  if (idx >= COUT * KTOT) return;
  int o  = idx / KTOT;
  int r  = idx - o * KTOT;
  int kw = r >> 9;
  int c  = r & 511;
  wt[idx] = (__bf16)k[(o * CIN + c) * 5 + kw];
}

// stage one half-tile (128 rows x 64 bf16 = 16KiB): 2 x global_load_lds(16B)/thread
#define STAGE_A(buf, h, kt) do { \
    char* d_ = (char*)&Ab[buf][h][0][0]; \
    gload_lds16(Xb + offA##h##0 + (kt)*64, d_ + dof0); \
    gload_lds16(Xb + offA##h##1 + (kt)*64, d_ + dof1); } while (0)
#define STAGE_B(buf, h, kt) do { \
    char* d_ = (char*)&Bb[buf][h][0][0]; \
    gload_lds16(Wt + offB##h##0 + (kt)*64, d_ + dof0); \
    gload_lds16(Wt + offB##h##1 + (kt)*64, d_ + dof1); } while (0)

#define RD_A(mi, ks) (*(const bf16x8*)(Abase + ((mi)*16 + frow)*128 + ((((ks)*64 + fkb)) ^ xorv)))
#define RD_B(nj, ks) (*(const bf16x8*)(Bbase + (brow0 + (nj)*16 + frow)*128 + ((((ks)*64 + fkb)) ^ xorv)))

__global__ __launch_bounds__(512, 2)
void tdnn_gemm_kernel(const __bf16* __restrict__ Xb, const __bf16* __restrict__ Wt,
                      const float* __restrict__ bias, float* __restrict__ out) {
  // 2 K-tile buffers x 2 halves x 128 rows x 64 bf16 (A and B) = 128 KiB
  __shared__ __bf16 Ab[2][2][128][64];
  __shared__ __bf16 Bb[2][2][128][64];

  const int tid  = threadIdx.x;
  const int wave = tid >> 6;
  const int lane = tid & 63;
  const int wr = wave >> 2;          // 0..1 : 128-row band (= A half)
  const int wc = wave & 3;           // 0..3 : 64-col band

  // bijective XCD swizzle: 498 = 8*62 + 2
  int bid = blockIdx.x;
  int xcd = bid & 7, jj = bid >> 3;
  const int q = NWG >> 3, r = NWG & 7;
  int swz = (xcd < r ? xcd * (q + 1) : r * (q + 1) + (xcd - r) * q) + jj;
  const int m0 = (swz >> 1) * 256;
  const int n0 = (swz & 1) * 256;

  // ---- per-thread staging offsets (pre-swizzled global source, linear LDS dest)
  // l in {0,1}: o16=l*512+tid; row=o16>>3; colb=(o16&7)<<4; src col = colb ^ ((row&7)<<4)
  int offA00, offA01, offA10, offA11, offB00, offB01, offB10, offB11, dof0, dof1;
  {
    int o16, row, ce, m, b, tt;
#define MKOFF(l, A0, A1, B0, B1, D) \
    o16 = (l)*512 + tid; row = o16 >> 3; \
    ce  = ((((o16 & 7) << 4) ^ ((row & 7) << 4)) >> 1); \
    D   = o16 * 16; \
    m = m0 + 0*128 + row; b = m / TOUT; tt = m - b * TOUT; \
    A0 = (b * SEQ + tt) * CIN + ce; \
    m = m0 + 1*128 + row; b = m / TOUT; tt = m - b * TOUT; \
    A1 = (b * SEQ + tt) * CIN + ce; \
    B0 = (n0 + 0*128 + row) * KTOT + ce; \
    B1 = (n0 + 1*128 + row) * KTOT + ce;
    MKOFF(0, offA00, offA10, offB00, offB10, dof0)
    MKOFF(1, offA01, offA11, offB01, offB11, dof1)
#undef MKOFF
  }

  // fragment read geometry
  const int frow = lane & 15;
  const int fkb  = (lane >> 4) << 4;       // 0,16,32,48 bytes
  const int xorv = (frow & 7) << 4;        // T2 read-side XOR (matches source pre-swizzle)
  const int brow0 = (wc & 1) * 64;         // local row base within B half (wc>>1)

  f32x4 acc[8][4];
  const f32x4 z = {0.f, 0.f, 0.f, 0.f};
#pragma unroll
  for (int i = 0; i < 8; i++)
#pragma unroll
    for (int j = 0; j < 4; j++) acc[i][j] = z;

  // ---- prologue: tile0 (all 4 halves) + tile1 A-halves; tile0 guaranteed landed
  STAGE_A(0, 0, 0); STAGE_A(0, 1, 0);
  STAGE_B(0, 0, 0); STAGE_B(0, 1, 0);
  STAGE_A(1, 0, 1); STAGE_A(1, 1, 1);
  VM4();
  BAR();

  for (int t = 0; t < NKT; ++t) {
    const int c  = t & 1;
    const int oo = c ^ 1;
    const bool s1 = (t + 1 < NKT);   // stage B halves of tile t+1 -> buf oo
    const bool s2 = (t + 2 < NKT);   // stage A halves of tile t+2 -> buf c

    const char* Abase = (const char*)&Ab[c][wr][0][0];
    const char* Bbase = (const char*)&Bb[c][wc >> 1][0][0];

    bf16x8 a[8][2], b[4][2];

    // ---- P1: read a[0:3], b[0:1]; stage (t+1, B-half0); MFMA Q1 = a[0:3] x b[0:1]
#pragma unroll
    for (int mi = 0; mi < 4; ++mi) { a[mi][0] = RD_A(mi, 0); a[mi][1] = RD_A(mi, 1); }
#pragma unroll
    for (int nj = 0; nj < 2; ++nj) { b[nj][0] = RD_B(nj, 0); b[nj][1] = RD_B(nj, 1); }
    if (s1) STAGE_B(oo, 0, t + 1);
    BAR(); LGKM0();
    PRIO(1);
#pragma unroll
    for (int mi = 0; mi < 4; ++mi)
#pragma unroll
      for (int nj = 0; nj < 2; ++nj) {
        acc[mi][nj] = __builtin_amdgcn_mfma_f32_16x16x32_bf16(a[mi][0], b[nj][0], acc[mi][nj], 0, 0, 0);
        acc[mi][nj] = __builtin_amdgcn_mfma_f32_16x16x32_bf16(a[mi][1], b[nj][1], acc[mi][nj], 0, 0, 0);
      }
    PRIO(0);
    BAR();

    // ---- P2: read a[4:7], b[2:3]; stage (t+1, B-half1); MFMA Q2 = a[4:7] x b[0:1]
#pragma unroll
    for (int mi = 4; mi < 8; ++mi) { a[mi][0] = RD_A(mi, 0); a[mi][1] = RD_A(mi, 1); }
#pragma unroll
    for (int nj = 2; nj < 4; ++nj) { b[nj][0] = RD_B(nj, 0); b[nj][1] = RD_B(nj, 1); }
    if (s1) STAGE_B(oo, 1, t + 1);
    BAR(); LGKM0();
    PRIO(1);
#pragma unroll
    for (int mi = 4; mi < 8; ++mi)
#pragma unroll
      for (int nj = 0; nj < 2; ++nj) {
        acc[mi][nj] = __builtin_amdgcn_mfma_f32_16x16x32_bf16(a[mi][0], b[nj][0], acc[mi][nj], 0, 0, 0);
        acc[mi][nj] = __builtin_amdgcn_mfma_f32_16x16x32_bf16(a[mi][1], b[nj][1], acc[mi][nj], 0, 0, 0);
      }
    PRIO(0);
    BAR();
    // buf c fully read by all waves at this point -> its A region is stageable.

    // ---- P3: stage (t+2, A-half0) into buf c; MFMA Q3 = a[0:3] x b[2:3]
    if (s2) STAGE_A(c, 0, t + 2);
    BAR();
    PRIO(1);
#pragma unroll
    for (int mi = 0; mi < 4; ++mi)
#pragma unroll
      for (int nj = 2; nj < 4; ++nj) {
        acc[mi][nj] = __builtin_amdgcn_mfma_f32_16x16x32_bf16(a[mi][0], b[nj][0], acc[mi][nj], 0, 0, 0);
        acc[mi][nj] = __builtin_amdgcn_mfma_f32_16x16x32_bf16(a[mi][1], b[nj][1], acc[mi][nj], 0, 0, 0);
      }
    PRIO(0);
    BAR();

    // ---- P4: stage (t+2, A-half1); counted wait (4 loads = t+2 A-halves in flight)
    if (s2) STAGE_A(c, 1, t + 2);
    if (s2) { VM4(); } else { VM0(); }
    BAR();
    PRIO(1);
#pragma unroll
    for (int mi = 4; mi < 8; ++mi)
#pragma unroll
      for (int nj = 2; nj < 4; ++nj) {
        acc[mi][nj] = __builtin_amdgcn_mfma_f32_16x16x32_bf16(a[mi][0], b[nj][0], acc[mi][nj], 0, 0, 0);
        acc[mi][nj] = __builtin_amdgcn_mfma_f32_16x16x32_bf16(a[mi][1], b[nj][1], acc[mi][nj], 0, 0, 0);
      }
    PRIO(0);
    BAR();
  }

  // ---- epilogue: bias + relu + store. C/D map: col=lane&15, row=(lane>>4)*4+reg
  const int ccol = lane & 15;
  const int crow = (lane >> 4) * 4;
  float bv[4];
#pragma unroll
  for (int nj = 0; nj < 4; ++nj)
    bv[nj] = bias[n0 + wc * 64 + nj * 16 + ccol];

#pragma unroll
  for (int mi = 0; mi < 8; ++mi) {
    const int mrow = m0 + wr * 128 + mi * 16 + crow;
#pragma unroll
    for (int nj = 0; nj < 4; ++nj) {
      const int ocol = n0 + wc * 64 + nj * 16 + ccol;
#pragma unroll
      for (int j = 0; j < 4; ++j) {
        float v = acc[mi][nj][j] + bv[nj];
        v = v > 0.f ? v : 0.f;
        out[(size_t)(mrow + j) * COUT + ocol] = v;
      }
    }
  }
}

extern "C" void kernel_launch(void* const* d_in, const int* in_sizes, int n_in,
                              void* d_out, int out_size, void* d_ws, size_t ws_size,
                              hipStream_t stream) {
  const float* x      = (const float*)d_in[0];   // [64,1000,512] fp32
  const float* kernel = (const float*)d_in[1];   // [512,512,5]   fp32
  const float* bias   = (const float*)d_in[2];   // [512]         fp32
  float* out          = (float*)d_out;           // [64,996,512]  fp32

  __bf16* xb = (__bf16*)d_ws;
  __bf16* wt = (__bf16*)((char*)d_ws + (size_t)BATCH * SEQ * CIN * 2);

  const int nx = BATCH * SEQ * CIN;              // 32,768,000
  cvt_x_kernel<<<nx / 8 / 256, 256, 0, stream>>>(x, xb, nx);
  cvt_w_kernel<<<(COUT * KTOT + 255) / 256, 256, 0, stream>>>(kernel, wt);
  tdnn_gemm_kernel<<<NWG, 512, 0, stream>>>(xb, wt, bias, out);
}